// Round 6
// baseline (281.507 us; speedup 1.0000x reference)
//
#include <hip/hip_runtime.h>

// MultiscaleLLN: out = x / (gauss13x13(lum(x)) / dens + eps), 4 pyramid levels.
// Separable Gaussian; dens analytic via prefix sums.
// R4: XCD-aware block swizzle (kept).
// R5/R6: b128 LDS convs, phase-4 VGPR RGB prefetch, padded strides (kept).
// R7: per-pixel dwordx3 global access (kept for loads; division hoisted out
//     of the hot path this round — R7's regression was per-use decode VALU).
// R8: 2-tile software pipeline per block. Evidence: HBM bytes (R1), LDS issue
//     (R3), and VMEM line count (R7) all changed with dur pinned ~90 us; no
//     pipe >40% busy; CU idle >=50% with 8 resident blocks. Theory: barrier-
//     aligned phases convoy all co-resident waves into the phase-1 global-load
//     wait simultaneously. Fix: while tile t computes, tile t+1's halo is in
//     flight into registers; lum committed to LDS behind the existing barrier.
//     Grid 11008 -> 5504 pair-blocks (= 8*688, swizzle exact). LDS unchanged
//     17 KB; trades some occupancy (VGPR ~80) for always-in-flight loads.
// R9: identical resubmit — R8 bench died on container acquisition (infra,
//     same signature as R2 which passed on retry); kernel re-audited
//     (bounds/aliasing/barrier-uniformity/pair-decode) with no defect found.

#define NPIX   87040
#define EPSV   1e-3f
#define WSUM   0.9999f      // 0.2989 + 0.587 + 0.114
#define RAD    6
#define LW     80           // lum px per row: [tx0-8, tx0+72)
#define LWP    84           // padded stride for s_lum
#define RCP    68           // padded stride for s_rc/s_scale
#define LH     28           // lum rows: [ty0-6, ty0+22)
#define NPXH   (LH * LW)    // 2240 halo pixels per tile
#define NT     2            // tiles per block (pipelined)
#define NPAIR  (11008 / NT) // 5504
#define NXCD   8
#define CHUNK  (NPAIR / NXCD)  // 688, exact

// 1D Gaussian taps G1[d+6] = exp(-d^2/18)/sqrt(18*pi), d = -6..6
__device__ __constant__ float G1[13] = {
    0.01799699f, 0.03315904f, 0.05467002f, 0.08065689f, 0.10648267f,
    0.12579441f, 0.13298076f, 0.12579441f, 0.10648267f, 0.08065689f,
    0.05467002f, 0.03315904f, 0.01799699f
};
// prefix sums PRE[i] = sum_{j<i} G1[j]
__device__ __constant__ float PRE[14] = {
    0.00000000f, 0.01799699f, 0.05115603f, 0.10582605f, 0.18648294f,
    0.29296561f, 0.41876002f, 0.55174078f, 0.67753519f, 0.78401786f,
    0.86467475f, 0.91934477f, 0.95250381f, 0.97050080f
};

struct F3 { float x, y, z; };   // 12 B -> global_load/store_dwordx3

// tiles within a pair never straddle a level boundary (all boundaries even)
__device__ __forceinline__ void decode_tile(int bid, const float* x, float* out,
    const float*& xb, float*& ob, int& w, int& h, int& tx0, int& ty0) {
    int img, tl, txlog, off;
    if (bid < 8192)       { img = bid >> 6;                 tl = bid & 63; txlog = 2; h = 256; off = 0;     }
    else if (bid < 10240) { int r = bid - 8192;  img = r >> 4; tl = r & 15; txlog = 1; h = 128; off = 65536; }
    else if (bid < 10752) { int r = bid - 10240; img = r >> 2; tl = r & 3;  txlog = 0; h = 64;  off = 81920; }
    else                  { int r = bid - 10752; img = r >> 1; tl = r & 1;  txlog = 0; h = 32;  off = 86016; }
    w   = h;
    tx0 = (tl & ((1 << txlog) - 1)) << 6;
    ty0 = (tl >> txlog) << 4;
    xb  = x   + (size_t)img * (NPIX * 3) + (size_t)off * 3;
    ob  = out + (size_t)img * (NPIX * 3) + (size_t)off * 3;
}

__global__ __launch_bounds__(256)
void mslln_kernel(const float* __restrict__ x, float* __restrict__ out) {
    // s_scale aliases s_lum rows 0..15 (s_lum dead after row conv; barriers
    // separate every writer/reader pair).
    __shared__ float s_mem[LH * LWP];          // 28*84*4 = 9408 B
    __shared__ float s_rc[LH][RCP];            // 28*68*4 = 7616 B  (tot 17024)
    float (*s_lum)[LWP]   = (float(*)[LWP])s_mem;
    float (*s_scale)[RCP] = (float(*)[RCP])s_mem;

    const int bphys = blockIdx.x;
    const int pair  = (bphys & (NXCD - 1)) * CHUNK + (bphys >> 3);
    const int t     = threadIdx.x;

    // loop-invariant halo coords: i = t + 256k -> (row,col) in 28x80, packed
    int hrc[9];
#pragma unroll
    for (int k = 0; k < 9; k++) {
        int i = t + (k << 8);
        int r = i / LW;
        hrc[k] = (r << 7) | (i - r * LW);
    }
    const bool h8   = (t < NPXH - 8 * 256);   // k=8 valid for t<192
    const int  prow = t >> 6;                 // phase-4 base row
    const int  pcol = t & 63;                 // phase-4 col

    // ---- prologue: tile 0 halo -> regs -> lum -> LDS; RGB0 prefetch ----
    const float* xb; float* ob; int w, h, tx0, ty0;
    decode_tile(pair * NT, x, out, xb, ob, w, h, tx0, ty0);

    F3 raw[9];
#pragma unroll
    for (int k = 0; k < 9; k++) {
        raw[k].x = 0.f; raw[k].y = 0.f; raw[k].z = 0.f;
        if (k < 8 || h8) {
            int gy = ty0 + (hrc[k] >> 7) - RAD;
            int gx = tx0 + (hrc[k] & 127) - 8;
            if (gy >= 0 && gy < h && gx >= 0 && gx < w)
                raw[k] = *(const F3*)(xb + ((size_t)gy * w + gx) * 3);
        }
    }
#pragma unroll
    for (int k = 0; k < 9; k++)
        if (k < 8 || h8)
            s_lum[hrc[k] >> 7][hrc[k] & 127] =
                0.2989f * raw[k].x + 0.587f * raw[k].y + 0.114f * raw[k].z;

    F3 pf[4];
#pragma unroll
    for (int j = 0; j < 4; j++) {
        pf[j].x = 0.f; pf[j].y = 0.f; pf[j].z = 0.f;
        if (tx0 + pcol < w)
            pf[j] = *(const F3*)(xb + ((size_t)(ty0 + prow + 4 * j) * w + tx0 + pcol) * 3);
    }
    __syncthreads();

    // ---- pipelined tile loop ----
    const float* xbn; float* obn; int wn, hn, txn, tyn;
#pragma unroll
    for (int tt = 0; tt < NT; tt++) {
        // issue next tile's halo loads: in flight under this tile's convs
        if (tt + 1 < NT) {
            decode_tile(pair * NT + tt + 1, x, out, xbn, obn, wn, hn, txn, tyn);
#pragma unroll
            for (int k = 0; k < 9; k++) {
                raw[k].x = 0.f; raw[k].y = 0.f; raw[k].z = 0.f;
                if (k < 8 || h8) {
                    int gy = tyn + (hrc[k] >> 7) - RAD;
                    int gx = txn + (hrc[k] & 127) - 8;
                    if (gy >= 0 && gy < hn && gx >= 0 && gx < wn)
                        raw[k] = *(const F3*)(xbn + ((size_t)gy * wn + gx) * 3);
                }
            }
        }

        // row conv: 28 rows x 16 groups of 4 = 448 groups (taps c+2..c+14)
#pragma unroll
        for (int k2 = 0; k2 < 2; k2++) {
            int gi = t + (k2 << 8);
            if (gi < 448) {
                int r  = gi >> 4;
                int c4 = (gi & 15) << 2;
                float a[20];
#pragma unroll
                for (int m = 0; m < 5; m++)
                    *(float4*)&a[m << 2] = *(const float4*)&s_lum[r][c4 + (m << 2)];
                float s0 = 0.f, s1 = 0.f, s2 = 0.f, s3 = 0.f;
#pragma unroll
                for (int j = 0; j < 13; j++) {
                    float gj = G1[j];
                    s0 += a[2 + j] * gj;
                    s1 += a[3 + j] * gj;
                    s2 += a[4 + j] * gj;
                    s3 += a[5 + j] * gj;
                }
                *(float4*)&s_rc[r][c4] = make_float4(s0, s1, s2, s3);
            }
        }
        __syncthreads();

        // col conv + analytic dens -> s_scale (aliases s_lum, now dead)
        {
            int ly = t >> 4, lx4 = (t & 15) << 2;
            if (tx0 + lx4 < w) {
                float4 acc = {0.f, 0.f, 0.f, 0.f};
#pragma unroll
                for (int j = 0; j < 13; j++) {
                    float4 v = *(const float4*)&s_rc[ly + j][lx4];
                    float gj = G1[j];
                    acc.x += v.x * gj; acc.y += v.y * gj;
                    acc.z += v.z * gj; acc.w += v.w * gj;
                }
                int gy = ty0 + ly;
                int ylo = min(RAD, gy), yhi = min(RAD, h - 1 - gy);
                float Sy = PRE[RAD + yhi + 1] - PRE[RAD - ylo];
                float4 sc;
#pragma unroll
                for (int d = 0; d < 4; d++) {
                    int gx = tx0 + lx4 + d;
                    int xlo = min(RAD, gx), xhi = min(RAD, w - 1 - gx);
                    float Sx = PRE[RAD + xhi + 1] - PRE[RAD - xlo];
                    float dens = WSUM * Sy * Sx;
                    float s = (d == 0) ? acc.x : (d == 1) ? acc.y : (d == 2) ? acc.z : acc.w;
                    float r = dens / (s + EPSV * dens);   // == 1/(s/dens + eps)
                    if (d == 0) sc.x = r; else if (d == 1) sc.y = r;
                    else if (d == 2) sc.z = r; else sc.w = r;
                }
                *(float4*)&s_scale[ly][lx4] = sc;
            }
        }
        __syncthreads();

        // phase 4: scale prefetched RGB, per-pixel store
        if (tx0 + pcol < w) {
#pragma unroll
            for (int j = 0; j < 4; j++) {
                float sc = s_scale[prow + 4 * j][pcol];
                F3 v = pf[j];
                v.x *= sc; v.y *= sc; v.z *= sc;
                *(F3*)(ob + ((size_t)(ty0 + prow + 4 * j) * w + tx0 + pcol) * 3) = v;
            }
        }

        if (tt + 1 < NT) {
            __syncthreads();      // all s_scale reads done before lum overwrite
            // commit next tile's lum (vmcnt wait on raw[], long since issued)
#pragma unroll
            for (int k = 0; k < 9; k++)
                if (k < 8 || h8)
                    s_lum[hrc[k] >> 7][hrc[k] & 127] =
                        0.2989f * raw[k].x + 0.587f * raw[k].y + 0.114f * raw[k].z;
            // RGB prefetch for next tile (L1-hot: halo loads covered it)
#pragma unroll
            for (int j = 0; j < 4; j++) {
                pf[j].x = 0.f; pf[j].y = 0.f; pf[j].z = 0.f;
                if (txn + pcol < wn)
                    pf[j] = *(const F3*)(xbn + ((size_t)(tyn + prow + 4 * j) * wn + txn + pcol) * 3);
            }
            xb = xbn; ob = obn; w = wn; h = hn; tx0 = txn; ty0 = tyn;
            __syncthreads();      // lum visible for next row conv
        }
    }
}

extern "C" void kernel_launch(void* const* d_in, const int* in_sizes, int n_in,
                              void* d_out, int out_size, void* d_ws, size_t ws_size,
                              hipStream_t stream) {
    const float* x = (const float*)d_in[0];
    float* out = (float*)d_out;
    mslln_kernel<<<NPAIR, 256, 0, stream>>>(x, out);
}

// Round 7
// 261.996 us; speedup vs baseline: 1.0745x; 1.0745x over previous
//
#include <hip/hip_runtime.h>

// MultiscaleLLN: out = x / (gauss13x13(lum(x)) / dens + eps), 4 pyramid levels.
// Separable Gaussian; dens analytic via prefix sums.
// R4: XCD-aware swizzle (kept). R5/R6: b128 LDS convs, phase-4 VGPR RGB
// prefetch, padded strides (kept — best measured 89.5 us/dispatch).
// R8/R9: 2-tile pipeline REVERTED (126 us; occupancy collapsed 73->40%).
// R10: persistent blocks. Evidence across 5 kernels: dur tracks achieved
//   occupancy; total VALU-busy-time constant ~32 us-equiv; per-block internals
//   (bytes, LDS ops, VMEM lines, prefetch) all neutral. The 73% occupancy
//   ceiling matches the 11008-block grid's ~5.4 residency rounds (ramp+drain
//   +turnaround). Fix: grid = 2048 blocks (8/CU = wave cap), each loops over
//   5-6 tiles with the UNCHANGED R3 phase code + one end-of-iter barrier
//   (s_scale aliases s_lum across iterations). Assignment keeps XCD locality:
//   block b -> xcd=b&7, slot=b>>3; step j runs tile xcd*1376 + j*256 + slot,
//   so each XCD's 256 resident blocks cover 256 contiguous tiles at all times
//   (R1's L2 window preserved). Utilization ceiling 11008/(2048*6) = 89.6%.

#define NPIX   87040
#define EPSV   1e-3f
#define WSUM   0.9999f      // 0.2989 + 0.587 + 0.114
#define RAD    6
#define LW     80           // lum px per row: [tx0-8, tx0+72)
#define LWP    84           // padded stride for s_lum
#define RCP    68           // padded stride for s_rc/s_scale
#define LH     28           // lum rows: [ty0-6, ty0+22)
#define NG     (LH * 20)    // 560 groups of 4 px
#define NXCD   8
#define TPX    1376         // tiles per XCD (11008/8)
#define NRES   2048         // persistent grid: 8 blocks/CU * 256 CU

// 1D Gaussian taps G1[d+6] = exp(-d^2/18)/sqrt(18*pi), d = -6..6
__device__ __constant__ float G1[13] = {
    0.01799699f, 0.03315904f, 0.05467002f, 0.08065689f, 0.10648267f,
    0.12579441f, 0.13298076f, 0.12579441f, 0.10648267f, 0.08065689f,
    0.05467002f, 0.03315904f, 0.01799699f
};
// prefix sums PRE[i] = sum_{j<i} G1[j]
__device__ __constant__ float PRE[14] = {
    0.00000000f, 0.01799699f, 0.05115603f, 0.10582605f, 0.18648294f,
    0.29296561f, 0.41876002f, 0.55174078f, 0.67753519f, 0.78401786f,
    0.86467475f, 0.91934477f, 0.95250381f, 0.97050080f
};

__device__ __forceinline__ void decode_tile(int bid, const float* x, float* out,
    const float*& xb, float*& ob, int& w, int& tx0, int& ty0) {
    int img, tl, txlog, h, off;
    if (bid < 8192)       { img = bid >> 6;                 tl = bid & 63; txlog = 2; h = 256; off = 0;     }
    else if (bid < 10240) { int r = bid - 8192;  img = r >> 4; tl = r & 15; txlog = 1; h = 128; off = 65536; }
    else if (bid < 10752) { int r = bid - 10240; img = r >> 2; tl = r & 3;  txlog = 0; h = 64;  off = 81920; }
    else                  { int r = bid - 10752; img = r >> 1; tl = r & 1;  txlog = 0; h = 32;  off = 86016; }
    w   = h;
    tx0 = (tl & ((1 << txlog) - 1)) << 6;
    ty0 = (tl >> txlog) << 4;
    xb  = x   + (size_t)img * (NPIX * 3) + (size_t)off * 3;
    ob  = out + (size_t)img * (NPIX * 3) + (size_t)off * 3;
}

__global__ __launch_bounds__(256)
void mslln_kernel(const float* __restrict__ x, float* __restrict__ out) {
    // s_scale aliases s_lum (s_lum dead after row conv; barriers fence all
    // writer/reader pairs, incl. the end-of-iteration overwrite).
    __shared__ float s_mem[LH * LWP];          // 28*84*4 = 9408 B
    __shared__ float s_rc[LH][RCP];            // 28*68*4 = 7616 B  (tot 17024)
    float (*s_lum)[LWP]   = (float(*)[LWP])s_mem;
    float (*s_scale)[RCP] = (float(*)[RCP])s_mem;

    const int b    = blockIdx.x;
    const int xcd  = b & (NXCD - 1);           // dispatch round-robins XCDs
    const int slot = b >> 3;                   // 0..255 within XCD
    const int t    = threadIdx.x;
    const int nj   = (slot < TPX - 5 * 256) ? 6 : 5;   // slots <96 take a 6th tile

    // hoisted per-thread constants (loop-invariant)
    int g_r[3], g_c[3];
#pragma unroll
    for (int k = 0; k < 3; k++) {
        int i = t + (k << 8);
        int gr = i / 20;
        g_r[k] = gr; g_c[k] = i - gr * 20;
    }
    const int ly  = t >> 4;          // phase 3/4 row (16 rows)
    const int lx4 = (t & 15) << 2;   // phase 3/4 col group *4

    for (int j = 0; j < nj; j++) {
        const int bid = xcd * TPX + (j << 8) + slot;
        const float* xb; float* ob; int w, tx0, ty0;
        decode_tile(bid, x, out, xb, ob, w, tx0, ty0);
        const int h = w;

        // ---- Phase 1: vectorized load, lum -> LDS (4 px / thread-iter) ----
#pragma unroll
        for (int k = 0; k < 3; k++) {
            if (t + (k << 8) < NG) {
                int gr  = g_r[k];
                int gc  = g_c[k];
                int gy  = ty0 + gr - RAD;
                int gx0 = tx0 + (gc << 2) - 8;   // float index 3*gx0 is 16B-aligned
                float4 f0 = {0,0,0,0}, f1 = {0,0,0,0}, f2 = {0,0,0,0};
                if (gy >= 0 && gy < h) {
                    if (gx0 >= 0 && gx0 + 3 < w) {
                        const float4* p = (const float4*)(xb + ((size_t)gy * w + gx0) * 3);
                        f0 = p[0]; f1 = p[1]; f2 = p[2];
                    } else {
                        float v[12];
#pragma unroll
                        for (int c = 0; c < 12; c++) v[c] = 0.f;
#pragma unroll
                        for (int c = 0; c < 4; c++) {
                            int gx = gx0 + c;
                            if (gx >= 0 && gx < w) {
                                const float* s = xb + ((size_t)gy * w + gx) * 3;
                                v[3*c] = s[0]; v[3*c+1] = s[1]; v[3*c+2] = s[2];
                            }
                        }
                        f0 = make_float4(v[0], v[1], v[2],  v[3]);
                        f1 = make_float4(v[4], v[5], v[6],  v[7]);
                        f2 = make_float4(v[8], v[9], v[10], v[11]);
                    }
                }
                float l0 = 0.2989f*f0.x + 0.587f*f0.y + 0.114f*f0.z;
                float l1 = 0.2989f*f0.w + 0.587f*f1.x + 0.114f*f1.y;
                float l2 = 0.2989f*f1.z + 0.587f*f1.w + 0.114f*f2.x;
                float l3 = 0.2989f*f2.y + 0.587f*f2.z + 0.114f*f2.w;
                *(float4*)&s_lum[gr][gc << 2] = make_float4(l0, l1, l2, l3);
            }
        }
        __syncthreads();

        // ---- Phase 2a: prefetch phase-4 RGB into VGPRs (L1/L2-hot) ----
        float4 f0p = {0,0,0,0}, f1p = {0,0,0,0}, f2p = {0,0,0,0};
        if (tx0 + lx4 < w) {                   // only false on L3 (w=32)
            const float4* p = (const float4*)(xb + ((size_t)(ty0 + ly) * w + tx0 + lx4) * 3);
            f0p = p[0]; f1p = p[1]; f2p = p[2];
        }

        // ---- Phase 2b: row conv, 28 rows x 16 groups of 4 = 448 groups ----
        // s_lum[r][c] holds px gx = tx0+c-8; output col c taps cols c+2..c+14.
#pragma unroll
        for (int k2 = 0; k2 < 2; k2++) {
            int gi = t + (k2 << 8);
            if (gi < 448) {
                int r  = gi >> 4;
                int c4 = (gi & 15) << 2;
                float a[20];
#pragma unroll
                for (int m = 0; m < 5; m++)
                    *(float4*)&a[m << 2] = *(const float4*)&s_lum[r][c4 + (m << 2)];
                float s0 = 0.f, s1 = 0.f, s2 = 0.f, s3 = 0.f;
#pragma unroll
                for (int jj = 0; jj < 13; jj++) {
                    float gj = G1[jj];
                    s0 += a[2 + jj] * gj;
                    s1 += a[3 + jj] * gj;
                    s2 += a[4 + jj] * gj;
                    s3 += a[5 + jj] * gj;
                }
                *(float4*)&s_rc[r][c4] = make_float4(s0, s1, s2, s3);
            }
        }
        __syncthreads();

        // ---- Phase 3: col conv + analytic dens -> s_scale (aliases s_lum) ----
        if (tx0 + lx4 < w) {
            float4 acc = {0.f, 0.f, 0.f, 0.f};
#pragma unroll
            for (int jj = 0; jj < 13; jj++) {
                float4 v = *(const float4*)&s_rc[ly + jj][lx4];
                float gj = G1[jj];
                acc.x += v.x * gj; acc.y += v.y * gj;
                acc.z += v.z * gj; acc.w += v.w * gj;
            }
            int gy = ty0 + ly;
            int ylo = min(RAD, gy), yhi = min(RAD, h - 1 - gy);
            float Sy = PRE[RAD + yhi + 1] - PRE[RAD - ylo];
            float4 sc;
#pragma unroll
            for (int d = 0; d < 4; d++) {
                int gx = tx0 + lx4 + d;
                int xlo = min(RAD, gx), xhi = min(RAD, w - 1 - gx);
                float Sx = PRE[RAD + xhi + 1] - PRE[RAD - xlo];
                float dens = WSUM * Sy * Sx;
                float s = (d == 0) ? acc.x : (d == 1) ? acc.y : (d == 2) ? acc.z : acc.w;
                float r = dens / (s + EPSV * dens);   // == 1/(s/dens + eps)
                if (d == 0) sc.x = r; else if (d == 1) sc.y = r;
                else if (d == 2) sc.z = r; else sc.w = r;
            }
            *(float4*)&s_scale[ly][lx4] = sc;
        }
        __syncthreads();

        // ---- Phase 4: scale prefetched RGB, vectorized store ----
        if (tx0 + lx4 < w) {
            float4 sc = *(const float4*)&s_scale[ly][lx4];
            f0p.x *= sc.x; f0p.y *= sc.x; f0p.z *= sc.x; f0p.w *= sc.y;
            f1p.x *= sc.y; f1p.y *= sc.y; f1p.z *= sc.z; f1p.w *= sc.z;
            f2p.x *= sc.z; f2p.y *= sc.w; f2p.z *= sc.w; f2p.w *= sc.w;
            float4* q = (float4*)(ob + ((size_t)(ty0 + ly) * w + tx0 + lx4) * 3);
            q[0] = f0p; q[1] = f1p; q[2] = f2p;
        }
        __syncthreads();   // s_scale reads done before next iter's s_lum writes
    }
}

extern "C" void kernel_launch(void* const* d_in, const int* in_sizes, int n_in,
                              void* d_out, int out_size, void* d_ws, size_t ws_size,
                              hipStream_t stream) {
    const float* x = (const float*)d_in[0];
    float* out = (float*)d_out;
    mslln_kernel<<<NRES, 256, 0, stream>>>(x, out);
}

// Round 8
// 245.689 us; speedup vs baseline: 1.1458x; 1.0664x over previous
//
#include <hip/hip_runtime.h>

// MultiscaleLLN: out = x / (gauss13x13(lum(x)) / dens + eps), 4 pyramid levels.
// Separable Gaussian; dens analytic via prefix sums.
// R4: XCD-aware block swizzle (kept). R5/R6: b128 LDS convs, phase-4 VGPR RGB
// prefetch, padded strides (kept — 89.5 us/dispatch, best).
// R8 2-tile pipe and R10 persistent blocks REVERTED (126 / 108 us).
// R11: memory-level-parallelism fix. VGPR_Count was 24: the phase-1 loop
//   reused f0-f2 across its 3 iterations, so the compiler (max-occupancy
//   target) serialized phase 1 into ~3-4 dependent HBM/L2 round-trips per
//   tile. This latency chain is the one invariant across every falsified
//   experiment (bytes R1, LDS ops R3, lines R7 — all neutral). Fix: issue all
//   9 halo float4 loads into distinct regs A[3][3] BEFORE any use (one
//   round-trip), fallback/consume after; __launch_bounds__(256,8) caps VGPR
//   at 64 so 8 blocks/CU occupancy is retained by construction.

#define NPIX   87040
#define EPSV   1e-3f
#define WSUM   0.9999f      // 0.2989 + 0.587 + 0.114
#define RAD    6
#define LW     80           // lum px per row: [tx0-8, tx0+72)
#define LWP    84           // padded stride for s_lum
#define RCP    68           // padded stride for s_rc/s_scale
#define LH     28           // lum rows: [ty0-6, ty0+22)
#define NG     (LH * 20)    // 560 groups of 4 px
#define NBLK   11008
#define NXCD   8
#define CHUNK  (NBLK / NXCD)   // 1376, exact

// 1D Gaussian taps G1[d+6] = exp(-d^2/18)/sqrt(18*pi), d = -6..6
__device__ __constant__ float G1[13] = {
    0.01799699f, 0.03315904f, 0.05467002f, 0.08065689f, 0.10648267f,
    0.12579441f, 0.13298076f, 0.12579441f, 0.10648267f, 0.08065689f,
    0.05467002f, 0.03315904f, 0.01799699f
};
// prefix sums PRE[i] = sum_{j<i} G1[j]
__device__ __constant__ float PRE[14] = {
    0.00000000f, 0.01799699f, 0.05115603f, 0.10582605f, 0.18648294f,
    0.29296561f, 0.41876002f, 0.55174078f, 0.67753519f, 0.78401786f,
    0.86467475f, 0.91934477f, 0.95250381f, 0.97050080f
};

__global__ __launch_bounds__(256, 8)
void mslln_kernel(const float* __restrict__ x, float* __restrict__ out) {
    // s_scale aliases s_lum: s_lum dead after phase 2, barrier before phase 3.
    __shared__ float s_mem[LH * LWP];          // 28*84*4 = 9408 B
    __shared__ float s_rc[LH][RCP];            // 28*68*4 = 7616 B  (tot 17024)
    float (*s_lum)[LWP]   = (float(*)[LWP])s_mem;
    float (*s_scale)[RCP] = (float(*)[RCP])s_mem;

    const int bphys = blockIdx.x;
    const int bid   = (bphys & (NXCD - 1)) * CHUNK + (bphys >> 3);
    const int t     = threadIdx.x;

    // block -> (level, image, tile); tiles are 64x16 outputs
    int img, tl, txlog, h, off;
    if (bid < 8192)       { img = bid >> 6;                 tl = bid & 63; txlog = 2; h = 256; off = 0;     }
    else if (bid < 10240) { int r = bid - 8192;  img = r >> 4; tl = r & 15; txlog = 1; h = 128; off = 65536; }
    else if (bid < 10752) { int r = bid - 10240; img = r >> 2; tl = r & 3;  txlog = 0; h = 64;  off = 81920; }
    else                  { int r = bid - 10752; img = r >> 1; tl = r & 1;  txlog = 0; h = 32;  off = 86016; }
    const int w   = h;
    const int tx0 = (tl & ((1 << txlog) - 1)) << 6;  // *64
    const int ty0 = (tl >> txlog) << 4;              // *16

    const float* __restrict__ xb = x   + (size_t)img * (NPIX * 3) + (size_t)off * 3;
    float*       __restrict__ ob = out + (size_t)img * (NPIX * 3) + (size_t)off * 3;

    // ---- Phase 1a: ISSUE all 9 halo float4 loads into distinct registers
    //      (single memory round-trip; nothing consumes a load before all are
    //      in flight) ----
    float4 A[3][3];
    int   grk[3], gck[3];
    bool  inrk[3], fastk[3];
#pragma unroll
    for (int k = 0; k < 3; k++) {
        unsigned i = t + k * 256;
        int gr  = i / 20;
        int gc  = i - gr * 20;
        grk[k] = gr; gck[k] = gc;
        int gy  = ty0 + gr - RAD;
        int gx0 = tx0 + (gc << 2) - 8;   // float index 3*gx0 is 16B-aligned
        bool inr  = (i < NG) && gy >= 0 && gy < h;
        bool fast = inr && gx0 >= 0 && gx0 + 3 < w;
        inrk[k] = inr; fastk[k] = fast;
        A[k][0] = make_float4(0,0,0,0);
        A[k][1] = make_float4(0,0,0,0);
        A[k][2] = make_float4(0,0,0,0);
        if (fast) {
            const float4* p = (const float4*)(xb + ((size_t)gy * w + gx0) * 3);
            A[k][0] = p[0]; A[k][1] = p[1]; A[k][2] = p[2];
        }
    }

    // ---- Phase 1b: slow-path gather (edge tiles only; L2-hot) ----
#pragma unroll
    for (int k = 0; k < 3; k++) {
        if (inrk[k] && !fastk[k]) {
            int gy  = ty0 + grk[k] - RAD;
            int gx0 = tx0 + (gck[k] << 2) - 8;
            float v[12];
#pragma unroll
            for (int c = 0; c < 12; c++) v[c] = 0.f;
#pragma unroll
            for (int c = 0; c < 4; c++) {
                int gx = gx0 + c;
                if (gx >= 0 && gx < w) {
                    const float* s = xb + ((size_t)gy * w + gx) * 3;
                    v[3*c] = s[0]; v[3*c+1] = s[1]; v[3*c+2] = s[2];
                }
            }
            A[k][0] = make_float4(v[0], v[1], v[2],  v[3]);
            A[k][1] = make_float4(v[4], v[5], v[6],  v[7]);
            A[k][2] = make_float4(v[8], v[9], v[10], v[11]);
        }
    }

    // ---- Phase 1c: consume -> lum -> LDS ----
#pragma unroll
    for (int k = 0; k < 3; k++) {
        if (t + k * 256 < NG) {
            float4 f0 = A[k][0], f1 = A[k][1], f2 = A[k][2];
            float l0 = 0.2989f*f0.x + 0.587f*f0.y + 0.114f*f0.z;
            float l1 = 0.2989f*f0.w + 0.587f*f1.x + 0.114f*f1.y;
            float l2 = 0.2989f*f1.z + 0.587f*f1.w + 0.114f*f2.x;
            float l3 = 0.2989f*f2.y + 0.587f*f2.z + 0.114f*f2.w;
            *(float4*)&s_lum[grk[k]][gck[k] << 2] = make_float4(l0, l1, l2, l3);
        }
    }
    __syncthreads();

    // ---- Phase 2a: prefetch phase-4 RGB into VGPRs (L1/L2-hot from phase 1;
    //      latency hides under the row conv below) ----
    const int p4_gr  = t >> 4;               // 16 rows
    const int p4_gc  = t & 15;               // 16 groups of 4 px
    const int p4_gx0 = tx0 + (p4_gc << 2);
    float4 f0p = {0,0,0,0}, f1p = {0,0,0,0}, f2p = {0,0,0,0};
    if (p4_gx0 < w) {                        // only false on L3 (w=32)
        const float4* p = (const float4*)(xb + ((size_t)(ty0 + p4_gr) * w + p4_gx0) * 3);
        f0p = p[0]; f1p = p[1]; f2p = p[2];
    }

    // ---- Phase 2b: row conv, 28 rows x 16 groups of 4 = 448 groups ----
    // s_lum[r][c] holds pixel gx = tx0 + c - 8; output col c taps cols c+2..c+14.
#pragma unroll
    for (int k = 0; k < 2; k++) {
        int gi = t + (k << 8);
        if (gi < 448) {
            int r  = gi >> 4;
            int c4 = (gi & 15) << 2;
            float a[20];
#pragma unroll
            for (int m = 0; m < 5; m++)
                *(float4*)&a[m << 2] = *(const float4*)&s_lum[r][c4 + (m << 2)];
            float s0 = 0.f, s1 = 0.f, s2 = 0.f, s3 = 0.f;
#pragma unroll
            for (int j = 0; j < 13; j++) {
                float gj = G1[j];
                s0 += a[2 + j] * gj;
                s1 += a[3 + j] * gj;
                s2 += a[4 + j] * gj;
                s3 += a[5 + j] * gj;
            }
            *(float4*)&s_rc[r][c4] = make_float4(s0, s1, s2, s3);
        }
    }
    __syncthreads();

    // ---- Phase 3: col conv (float4 rows) + analytic dens -> scale ----
    {
        int ly  = t >> 4;
        int lx4 = (t & 15) << 2;
        if (tx0 + lx4 < w) {                 // only false on L3 (w=32)
            float4 acc = {0.f, 0.f, 0.f, 0.f};
#pragma unroll
            for (int j = 0; j < 13; j++) {
                float4 v = *(const float4*)&s_rc[ly + j][lx4];
                float gj = G1[j];
                acc.x += v.x * gj; acc.y += v.y * gj;
                acc.z += v.z * gj; acc.w += v.w * gj;
            }
            int gy = ty0 + ly;
            int ylo = min(RAD, gy), yhi = min(RAD, h - 1 - gy);
            float Sy = PRE[RAD + yhi + 1] - PRE[RAD - ylo];
            float4 sc;
#pragma unroll
            for (int d = 0; d < 4; d++) {
                int gx = tx0 + lx4 + d;
                int xlo = min(RAD, gx), xhi = min(RAD, w - 1 - gx);
                float Sx = PRE[RAD + xhi + 1] - PRE[RAD - xlo];
                float dens = WSUM * Sy * Sx;
                float s = (d == 0) ? acc.x : (d == 1) ? acc.y : (d == 2) ? acc.z : acc.w;
                float r = dens / (s + EPSV * dens);   // == 1/(s/dens + eps)
                if (d == 0) sc.x = r; else if (d == 1) sc.y = r;
                else if (d == 2) sc.z = r; else sc.w = r;
            }
            *(float4*)&s_scale[ly][lx4] = sc;
        }
    }
    __syncthreads();

    // ---- Phase 4: scale retained RGB, vectorized store ----
    if (p4_gx0 < w) {
        float4 sc = *(const float4*)&s_scale[p4_gr][p4_gc << 2];
        f0p.x *= sc.x; f0p.y *= sc.x; f0p.z *= sc.x; f0p.w *= sc.y;
        f1p.x *= sc.y; f1p.y *= sc.y; f1p.z *= sc.z; f1p.w *= sc.z;
        f2p.x *= sc.z; f2p.y *= sc.w; f2p.z *= sc.w; f2p.w *= sc.w;
        float4* q = (float4*)(ob + ((size_t)(ty0 + p4_gr) * w + p4_gx0) * 3);
        q[0] = f0p; q[1] = f1p; q[2] = f2p;
    }
}

extern "C" void kernel_launch(void* const* d_in, const int* in_sizes, int n_in,
                              void* d_out, int out_size, void* d_ws, size_t ws_size,
                              hipStream_t stream) {
    const float* x = (const float*)d_in[0];
    float* out = (float*)d_out;
    mslln_kernel<<<NBLK, 256, 0, stream>>>(x, out);
}